// Round 1
// baseline (111.511 us; speedup 1.0000x reference)
//
#include <hip/hip_runtime.h>
#include <hip/hip_bf16.h>
#include <cstdint>
#include <cstddef>
#include <math.h>

// Problem constants (reference: B=4096, D=256, T=0.5)
#define BSZ   4096
#define NROW  8192          // 2*B
#define DIM   256
#define INV_T 2.0f
#define EPS_N 1e-8f

typedef __attribute__((ext_vector_type(8))) short bf16x8;   // 8 bf16 = 4 VGPRs
typedef __attribute__((ext_vector_type(4))) float f32x4;

__device__ __forceinline__ unsigned short f2bf(float x) {
    __hip_bfloat16 h = __float2bfloat16(x);
    return __builtin_bit_cast(unsigned short, h);
}

// async global->LDS 16B helper (wave-uniform LDS base + lane*16 layout)
__device__ __forceinline__ void load_lds16(const void* g, void* l) {
    __builtin_amdgcn_global_load_lds(
        (const __attribute__((address_space(1))) void*)g,
        (__attribute__((address_space(3))) void*)l,
        16, 0, 0);
}

// ---------------------------------------------------------------------------
// Kernel 1: row-normalize concat(z1,z2), fp32 math, bf16 out. One row/wave,
// float4 loads (16B/lane), no block barriers. Also zeroes rowsum[row].
__global__ __launch_bounds__(256)
void nt_normalize(const float* __restrict__ z1,
                  const float* __restrict__ z2,
                  __hip_bfloat16* __restrict__ zn,
                  float* __restrict__ rowsum) {
    const int wave = threadIdx.x >> 6;
    const int lane = threadIdx.x & 63;
    const int row  = blockIdx.x * 4 + wave;
    const float* src = (row < BSZ) ? (z1 + (size_t)row * DIM)
                                   : (z2 + (size_t)(row - BSZ) * DIM);
    const float4 v = ((const float4*)src)[lane];
    float ss = v.x * v.x + v.y * v.y + v.z * v.z + v.w * v.w;
    #pragma unroll
    for (int off = 32; off; off >>= 1) ss += __shfl_xor(ss, off);
    const float rinv = 1.0f / fmaxf(sqrtf(ss), EPS_N);  // torch eps clamp
    ushort4 o;
    o.x = f2bf(v.x * rinv);
    o.y = f2bf(v.y * rinv);
    o.z = f2bf(v.z * rinv);
    o.w = f2bf(v.w * rinv);
    ((ushort4*)(zn + (size_t)row * DIM))[lane] = o;
    if (lane == 0) rowsum[row] = 0.0f;
}

// ---------------------------------------------------------------------------
// Kernel 2: tiled Zn·Znᵀ, upper triangle, 256x256 tiles (32 strips -> 528
// tiles), 512 threads = 8 waves in a 2x4 grid (128x64 output per wave).
// Theory-of-change vs previous 128² version:
//   (a) staged L2/L3 bytes halve (135 MB vs 266 MB),
//   (b) band-ordered, XCD-contiguous tile walk gives L2 reuse (B strip read
//       4x back-to-back, A band of 4 strips stays resident),
//   (c) double-buffered LDS (stage k+1 issued before compute k, one barrier
//       per K-step) hides staging latency at 1 block/CU,
//   (d) LDS ds_add reduction cuts global atomics 1.06M -> 270k.
// LDS XOR-swizzle identical to the verified 128² kernel: LDS[m][pos] holds
// global chunk pos^(m&7); global_load_lds dest stays the identity layout.
__global__ __launch_bounds__(512, 2)
void nt_gram(const __hip_bfloat16* __restrict__ zn,
             float* __restrict__ rowsum,
             float* __restrict__ pos) {
    __shared__ char lds[131072];   // A0|B0|A1|B1, 32 KB each

    // --- tile decode ---------------------------------------------------
    // Bands of 4 strips; within band: triangular head (bj=4b..4b+3), then
    // bj outer / bi inner groups of 4. O(b) = 130b - 8b^2 tiles precede
    // band b (O(8)=528). XCD k gets the contiguous run l = k*66 .. k*66+65.
    const int bidx = blockIdx.x;
    const int l = (bidx & 7) * 66 + (bidx >> 3);
    int b = 0;
    #pragma unroll
    for (int bb = 1; bb < 8; ++bb)
        if (l >= 130 * bb - 8 * bb * bb) b = bb;
    const int idx = l - (130 * b - 8 * b * b);
    int bi, bj;
    if (idx < 10) {  // triangular head: sizes {1,2,3,4}, starts {0,1,3,6}
        const int j0   = (idx >= 6) ? 3 : (idx >= 3) ? 2 : (idx >= 1) ? 1 : 0;
        const int toff = (j0 == 3) ? 6 : (j0 == 2) ? 3 : (j0 == 1) ? 1 : 0;
        bi = 4 * b + idx - toff;
        bj = 4 * b + j0;
    } else {
        bi = 4 * b + ((idx - 10) & 3);
        bj = 4 * b + 4 + ((idx - 10) >> 2);
    }

    const int t    = threadIdx.x;
    const int lane = t & 63;
    const int wave = t >> 6;
    const int wrow = (wave >> 2) * 128;   // 0 or 128
    const int wcol = (wave & 3) * 64;     // 0,64,128,192

    const __hip_bfloat16* Ag = zn + (size_t)bi * 256 * DIM;
    const __hip_bfloat16* Bg = zn + (size_t)bj * 256 * DIM;

    char* A0 = lds;
    char* B0 = lds + 32768;
    char* A1 = lds + 65536;
    char* B1 = lds + 98304;

    const int srow = t >> 3;                 // 0..63 per pass
    const int sc   = (t & 7) ^ (srow & 7);   // pre-swizzled global chunk
    const int q    = lane >> 4;
    const int r16  = lane & 15;
    const int sw   = r16 & 7;                // read-side swizzle key

    f32x4 acc[8][4] = {};

    auto STAGE = [&](int k0, char* As, char* Bs) {
        #pragma unroll
        for (int p = 0; p < 4; ++p) {
            const int row = p * 64 + srow;   // row&7 == srow&7, pass-invariant
            load_lds16(Ag + (size_t)row * DIM + k0 + sc * 8, As + p * 8192 + t * 16);
            load_lds16(Bg + (size_t)row * DIM + k0 + sc * 8, Bs + p * 8192 + t * 16);
        }
    };

    auto COMPUTE = [&](const char* As, const char* Bs) {
        #pragma unroll
        for (int kk = 0; kk < 64; kk += 32) {
            const int cc   = (kk >> 3) + q;       // chunk index within row
            const int cpos = (cc ^ sw) << 4;      // swizzled byte position
            bf16x8 af[8], bfr[4];
            #pragma unroll
            for (int mi = 0; mi < 8; ++mi)
                af[mi] = *(const bf16x8*)(As + (wrow + mi * 16 + r16) * 128 + cpos);
            #pragma unroll
            for (int ni = 0; ni < 4; ++ni)
                bfr[ni] = *(const bf16x8*)(Bs + (wcol + ni * 16 + r16) * 128 + cpos);
            #pragma unroll
            for (int mi = 0; mi < 8; ++mi)
                #pragma unroll
                for (int ni = 0; ni < 4; ++ni)
                    acc[mi][ni] = __builtin_amdgcn_mfma_f32_16x16x32_bf16(
                        af[mi], bfr[ni], acc[mi][ni], 0, 0, 0);
        }
    };

    // K pipeline: 4 steps of BK=64, double-buffered, stage issued pre-compute.
    STAGE(0, A0, B0);
    __syncthreads();
    STAGE(64, A1, B1);
    COMPUTE(A0, B0);
    __syncthreads();
    STAGE(128, A0, B0);
    COMPUTE(A1, B1);
    __syncthreads();
    STAGE(192, A1, B1);
    COMPUTE(A0, B0);
    __syncthreads();
    // buf0 is now dead: reuse its first 2 KB as LDS accumulators.
    float* rowacc = (float*)A0;            // [256]
    float* colacc = (float*)(A0 + 1024);   // [256]
    ((float*)A0)[t] = 0.0f;                // 512 threads zero 512 floats
    COMPUTE(A1, B1);                       // final K-step (reads buf1 only)
    __syncthreads();                       // zeros done before ds_add below

    // Epilogue. C/D layout: col=lane&15, row=(lane>>4)*4+reg (m89-verified).
    const int  c          = r16;
    const bool diag_block = (bi == bj);
    float colp[4] = {0.f, 0.f, 0.f, 0.f};

    #pragma unroll
    for (int mi = 0; mi < 8; ++mi) {
        #pragma unroll
        for (int r = 0; r < 4; ++r) {
            const int trow = wrow + mi * 16 + q * 4 + r;
            const int grow = bi * 256 + trow;
            float s = 0.f;
            #pragma unroll
            for (int ni = 0; ni < 4; ++ni) {
                const int gcol = bj * 256 + wcol + ni * 16 + c;
                const float val = acc[mi][ni][r];
                float e = __expf(val * INV_T);
                e = (grow == gcol) ? 0.f : e;   // exact diagonal exclusion
                s += e;
                colp[ni] += e;
                if (gcol == grow + BSZ) {       // positive pair (bj == bi+16)
                    pos[grow] = val;
                    pos[gcol] = val;            // symmetric partner
                }
            }
            s += __shfl_xor(s, 1);
            s += __shfl_xor(s, 2);
            s += __shfl_xor(s, 4);
            s += __shfl_xor(s, 8);
            if (c == 0) atomicAdd(&rowacc[trow], s);   // LDS ds_add
        }
    }
    if (!diag_block) {   // diag tiles: col sums would double-count (symmetry)
        #pragma unroll
        for (int ni = 0; ni < 4; ++ni) {
            float cs = colp[ni];
            cs += __shfl_xor(cs, 16);
            cs += __shfl_xor(cs, 32);
            if (q == 0) atomicAdd(&colacc[wcol + ni * 16 + c], cs);  // LDS
        }
    }
    __syncthreads();
    // One global atomic per row/col per block (512 total vs 2048 before).
    if (t < 256) {
        atomicAdd(&rowsum[bi * 256 + t], rowacc[t]);
    } else if (!diag_block) {
        atomicAdd(&rowsum[bj * 256 + (t - 256)], colacc[t - 256]);
    }
}

// ---------------------------------------------------------------------------
// Kernel 3: single block, 1024 threads; writes out[0] directly.
__global__ __launch_bounds__(1024)
void nt_finalize(const float* __restrict__ rowsum,
                 const float* __restrict__ pos,
                 float* __restrict__ out) {
    float v = 0.f;
    for (int i = threadIdx.x; i < NROW; i += 1024) {
        const float pl = pos[i] * INV_T;
        v += logf(__expf(pl) + rowsum[i]) - pl;
    }
    #pragma unroll
    for (int off = 32; off; off >>= 1) v += __shfl_xor(v, off);
    __shared__ float red[16];
    if ((threadIdx.x & 63) == 0) red[threadIdx.x >> 6] = v;
    __syncthreads();
    if (threadIdx.x == 0) {
        float s = 0.f;
        #pragma unroll
        for (int w = 0; w < 16; ++w) s += red[w];
        out[0] = s * (1.0f / NROW);
    }
}

// ---------------------------------------------------------------------------
extern "C" void kernel_launch(void* const* d_in, const int* in_sizes, int n_in,
                              void* d_out, int out_size, void* d_ws, size_t ws_size,
                              hipStream_t stream) {
    const float* z1 = (const float*)d_in[0];
    const float* z2 = (const float*)d_in[1];
    float* out = (float*)d_out;

    __hip_bfloat16* zn = (__hip_bfloat16*)d_ws;                       // 4 MB
    float* rowsum = (float*)((char*)d_ws + (size_t)NROW * DIM * 2);   // 32 KB
    float* pos    = rowsum + NROW;                                    // 32 KB

    nt_normalize<<<NROW / 4, 256, 0, stream>>>(z1, z2, zn, rowsum);
    nt_gram<<<528, 512, 0, stream>>>(zn, rowsum, pos);
    nt_finalize<<<1, 1024, 0, stream>>>(rowsum, pos, out);
}